// Round 17
// baseline (82.586 us; speedup 1.0000x reference)
//
#include <hip/hip_runtime.h>

typedef __attribute__((ext_vector_type(8))) short short8;
typedef __attribute__((ext_vector_type(4))) float f32x4;

#define EPS   1e-3f
#define ALPHA 0.3f

#define MFMA(a, b, c) __builtin_amdgcn_mfma_f32_16x16x32_bf16((a), (b), (c), 0, 0, 0)

__device__ __forceinline__ unsigned short f2bf(float f) {
    unsigned u = __float_as_uint(f);
    unsigned r = u + 0x7FFFu + ((u >> 16) & 1u);
    return (unsigned short)(r >> 16);
}
__device__ __forceinline__ float bf2f(unsigned short u) {
    return __uint_as_float((unsigned)u << 16);
}
__device__ __forceinline__ float lrelu(float v) { return v > 0.f ? v : ALPHA * v; }

// ---------------------------------------------------------------------------
// N1 prep (102 blocks), all-MFMA Wc (R16 verbatim).
// ---------------------------------------------------------------------------
__global__ __launch_bounds__(256) void prep_kernel(
    const float* __restrict__ W0, const float* __restrict__ Wd0,
    const float* __restrict__ W1, const float* __restrict__ Wd1,
    const float* __restrict__ b0, const float* __restrict__ bd0,
    const float* __restrict__ b1, const float* __restrict__ bd1,
    unsigned short* __restrict__ Wc0bT, unsigned short* __restrict__ Wc1bT,
    float* __restrict__ bcomb0, float* __restrict__ bcomb1)
{
    const int bid = blockIdx.x, t = threadIdx.x;
    if (bid < 100) {
        __shared__ unsigned short Ab[32][264];
        __shared__ unsigned short BbT[32][264];
        const float *Wsrc, *Wdsrc;
        unsigned short* Cdst;
        int ldc, ft, ct, arows;
        if (bid < 64) { ft = bid & 15; ct = bid >> 4; Wsrc = W0; Wdsrc = Wd0;
                        Cdst = Wc0bT; ldc = 512; arows = 512; }
        else { const int s = bid - 64; ft = s % 9; ct = s / 9;
               Wsrc = W1; Wdsrc = Wd1; Cdst = Wc1bT; ldc = 296; arows = 266; }

        {
            const int row = t >> 3, kc = t & 7;
            const int f = ft * 32 + row;
            if (f < arows) {
                const float* wp = Wsrc + (size_t)f * 256 + kc * 32;
#pragma unroll
                for (int i = 0; i < 8; ++i) {
                    const float4 v = ((const float4*)wp)[i];
                    Ab[row][kc * 32 + i * 4 + 0] = f2bf(v.x);
                    Ab[row][kc * 32 + i * 4 + 1] = f2bf(v.y);
                    Ab[row][kc * 32 + i * 4 + 2] = f2bf(v.z);
                    Ab[row][kc * 32 + i * 4 + 3] = f2bf(v.w);
                }
            } else {
#pragma unroll
                for (int i = 0; i < 8; ++i)
                    *(ushort4*)&Ab[row][kc * 32 + i * 4] = make_ushort4(0, 0, 0, 0);
            }
        }
        for (int idx = t; idx < 2048; idx += 256) {
            const int h = idx >> 3, c4 = idx & 7;
            const int cbase = ct * 32 + c4 * 4;
            float v[4];
            if (cbase + 3 < 100) {
                const float4 q = *(const float4*)&Wdsrc[(size_t)h * 100 + cbase];
                v[0] = q.x; v[1] = q.y; v[2] = q.z; v[3] = q.w;
            } else {
#pragma unroll
                for (int j = 0; j < 4; ++j)
                    v[j] = (cbase + j < 100) ? Wdsrc[(size_t)h * 100 + cbase + j] : 0.f;
            }
#pragma unroll
            for (int j = 0; j < 4; ++j) BbT[c4 * 4 + j][h] = f2bf(v[j]);
        }
        __syncthreads();

        const int lane = t & 63, w = t >> 6;
        const int cr = w & 1, fr = w >> 1, r = lane & 15, g = lane >> 4;
        const unsigned short* Ap = &BbT[cr * 16 + r][g * 8];
        const unsigned short* Bp = &Ab[fr * 16 + r][g * 8];
        f32x4 a0 = {0.f, 0.f, 0.f, 0.f}, a1 = {0.f, 0.f, 0.f, 0.f};
#pragma unroll
        for (int k0 = 0; k0 < 256; k0 += 64) {
            a0 = MFMA(*(const short8*)(Ap + k0),      *(const short8*)(Bp + k0),      a0);
            a1 = MFMA(*(const short8*)(Ap + k0 + 32), *(const short8*)(Bp + k0 + 32), a1);
        }
        const f32x4 acc = a0 + a1;
        const int crow = ct * 32 + cr * 16 + g * 4;
        const int fcol = ft * 32 + fr * 16 + r;
#pragma unroll
        for (int i = 0; i < 4; ++i)
            Cdst[(size_t)(crow + i) * ldc + fcol] = f2bf(acc[i]);
    } else {
        const float* bb = (bid == 100) ? b0 : b1;
        const float* Wd = (bid == 100) ? Wd0 : Wd1;
        const float* bd = (bid == 100) ? bd0 : bd1;
        float* o = (bid == 100) ? bcomb0 : bcomb1;
        if (t < 128) {
            float s = 0.f;
            if (t < 100) {
                s = bd[t];
                float s0 = 0.f, s1 = 0.f, s2 = 0.f, s3 = 0.f;
                for (int k = 0; k < 256; k += 4) {
                    s0 += bb[k]     * Wd[k * 100 + t];
                    s1 += bb[k + 1] * Wd[(k + 1) * 100 + t];
                    s2 += bb[k + 2] * Wd[(k + 2) * 100 + t];
                    s3 += bb[k + 3] * Wd[(k + 3) * 100 + t];
                }
                s += (s0 + s1) + (s2 + s3);
            }
            o[t] = s;
        }
    }
}

// ---------------------------------------------------------------------------
// N2 hm0: grid (32,12). yt<8: h0 = x@W0+b0; yt>=8: Mt0 = x@Wc0+bcomb0 (bf16).
// ---------------------------------------------------------------------------
__global__ __launch_bounds__(256) void hm0_mfma(
    const float* __restrict__ x, const float* __restrict__ W0,
    const unsigned short* __restrict__ Wc0bT,
    const float* __restrict__ b0, const float* __restrict__ bcomb0,
    float* __restrict__ h0, unsigned short* __restrict__ Mt0)
{
    __shared__ unsigned short At[32][520];
    __shared__ unsigned short Bt[32][520];

    const int t = threadIdx.x, xt = blockIdx.x, yt = blockIdx.y;

    {
        const int row = t >> 3, kc = t & 7;
        const float* xp = x + (size_t)(xt * 32 + row) * 512 + kc * 64;
#pragma unroll
        for (int i = 0; i < 8; ++i) {
            const float4 lo = ((const float4*)xp)[i * 2];
            const float4 hi = ((const float4*)xp)[i * 2 + 1];
            short8 p;
            p[0] = f2bf(lo.x); p[1] = f2bf(lo.y); p[2] = f2bf(lo.z); p[3] = f2bf(lo.w);
            p[4] = f2bf(hi.x); p[5] = f2bf(hi.y); p[6] = f2bf(hi.z); p[7] = f2bf(hi.w);
            *(short8*)&At[row][kc * 64 + i * 8] = p;
        }
    }
    if (yt < 8) {
        const int kc = t >> 5, n = t & 31, col0 = yt * 32;
        for (int kk = 0; kk < 64; kk += 2) {
            const int k = kc * 64 + kk;
            const float a = W0[(size_t)k * 256 + col0 + n];
            const float b = W0[(size_t)(k + 1) * 256 + col0 + n];
            const unsigned pk = (unsigned)f2bf(a) | ((unsigned)f2bf(b) << 16);
            *(unsigned*)&Bt[n][k] = pk;
        }
    } else {
        const int c = t >> 3, kc = t & 7;
        const unsigned short* bp = Wc0bT + (size_t)((yt - 8) * 32 + c) * 512 + kc * 64;
#pragma unroll
        for (int i = 0; i < 8; ++i)
            *(short8*)&Bt[c][kc * 64 + i * 8] = ((const short8*)bp)[i];
    }
    __syncthreads();

    const int lane = t & 63, w = t >> 6;
    const int wr = w >> 1, wn = w & 1, r = lane & 15, g = lane >> 4;
    const int lrA = wr * 16 + r, lrB = wn * 16 + r;
    f32x4 a0 = {0.f, 0.f, 0.f, 0.f}, a1 = {0.f, 0.f, 0.f, 0.f};
#pragma unroll
    for (int k0 = 0; k0 < 512; k0 += 64) {
        a0 = MFMA(*(const short8*)&At[lrA][k0 + g * 8],
                  *(const short8*)&Bt[lrB][k0 + g * 8], a0);
        a1 = MFMA(*(const short8*)&At[lrA][k0 + 32 + g * 8],
                  *(const short8*)&Bt[lrB][k0 + 32 + g * 8], a1);
    }
    const f32x4 acc = a0 + a1;
    const int orow0 = xt * 32 + wr * 16 + g * 4;

    if (yt < 8) {
        const int bcol = yt * 32 + wn * 16 + r;
        const float bv = b0[bcol];
#pragma unroll
        for (int i = 0; i < 4; ++i)
            h0[(size_t)(orow0 + i) * 256 + bcol] = acc[i] + bv;
    } else {
        const int c = (yt - 8) * 32 + wn * 16 + r;
        if (c < 100) {
            const int kq = c / 10, d = c - kq * 10;
            const float bv = bcomb0[c];
            unsigned short* dst = Mt0 + (size_t)kq * (1024 * 16)
                                + (size_t)orow0 * 16 + d;
#pragma unroll
            for (int i = 0; i < 4; ++i) dst[(size_t)i * 16] = f2bf(acc[i] + bv);
        }
    }
}

// ---------------------------------------------------------------------------
// N4 hm1: grid (32,12). A = a0b bf16 [1024][296]. yt<8: h1; yt>=8: Mt1 (bf16).
// ---------------------------------------------------------------------------
__global__ __launch_bounds__(256) void hm1_mfma(
    const unsigned short* __restrict__ a0b, const float* __restrict__ W1,
    const unsigned short* __restrict__ Wc1bT,
    const float* __restrict__ b1, const float* __restrict__ bcomb1,
    float* __restrict__ h1, unsigned short* __restrict__ Mt1)
{
    __shared__ unsigned short At[32][296];
    __shared__ unsigned short Bt[32][296];

    const int t = threadIdx.x, xt = blockIdx.x, yt = blockIdx.y;

    {
        const int row = t >> 3, kc = t & 7;
        const unsigned short* ap = a0b + (size_t)(xt * 32 + row) * 296;
        for (int i = kc; i < 37; i += 8)
            *(short8*)&At[row][i * 8] = ((const short8*)ap)[i];
    }
    if (yt < 8) {
        const int kc = t >> 5, n = t & 31, col0 = yt * 32;
        const int kkEnd = (kc == 7) ? 44 : 36;
        for (int kk = 0; kk < kkEnd; kk += 2) {
            const int k = kc * 36 + kk;
            const float a = (k < 266)     ? W1[(size_t)k * 256 + col0 + n] : 0.f;
            const float b = (k + 1 < 266) ? W1[(size_t)(k + 1) * 256 + col0 + n] : 0.f;
            const unsigned pk = (unsigned)f2bf(a) | ((unsigned)f2bf(b) << 16);
            *(unsigned*)&Bt[n][k] = pk;
        }
    } else {
        const int c = t >> 3, kc = t & 7;
        const unsigned short* bp = Wc1bT + (size_t)((yt - 8) * 32 + c) * 296;
        for (int i = kc; i < 37; i += 8)
            *(short8*)&Bt[c][i * 8] = ((const short8*)bp)[i];
    }
    __syncthreads();

    const int lane = t & 63, w = t >> 6;
    const int wr = w >> 1, wn = w & 1, r = lane & 15, g = lane >> 4;
    const int lrA = wr * 16 + r, lrB = wn * 16 + r;
    f32x4 a0 = {0.f, 0.f, 0.f, 0.f}, a1 = {0.f, 0.f, 0.f, 0.f};
#pragma unroll
    for (int k0 = 0; k0 < 256; k0 += 64) {
        a0 = MFMA(*(const short8*)&At[lrA][k0 + g * 8],
                  *(const short8*)&Bt[lrB][k0 + g * 8], a0);
        a1 = MFMA(*(const short8*)&At[lrA][k0 + 32 + g * 8],
                  *(const short8*)&Bt[lrB][k0 + 32 + g * 8], a1);
    }
    a0 = MFMA(*(const short8*)&At[lrA][256 + g * 8],
              *(const short8*)&Bt[lrB][256 + g * 8], a0);
    const f32x4 acc = a0 + a1;
    const int orow0 = xt * 32 + wr * 16 + g * 4;

    if (yt < 8) {
        const int bcol = yt * 32 + wn * 16 + r;
        const float bv = b1[bcol];
#pragma unroll
        for (int i = 0; i < 4; ++i)
            h1[(size_t)(orow0 + i) * 256 + bcol] = acc[i] + bv;
    } else {
        const int c = (yt - 8) * 32 + wn * 16 + r;
        if (c < 100) {
            const int kq = c / 10, d = c - kq * 10;
            const float bv = bcomb1[c];
            unsigned short* dst = Mt1 + (size_t)kq * (1024 * 16)
                                + (size_t)orow0 * 16 + d;
#pragma unroll
            for (int i = 0; i < 4; ++i) dst[(size_t)i * 16] = f2bf(acc[i] + bv);
        }
    }
}

// ---------------------------------------------------------------------------
// N3/N5 divln<TAIL>: grid 256 x 256 thr; block owns rows bid*4..+3 COMPLETE
// (all 10 k) -> no fences, LN tail fused in-block.
// Per k: stage Mt[k] [1024][16] bf16 -> Ms[buf] fp32 stride 11 (conflict-free,
// double-buffered: stage k+1 overlaps pair-loop k). Pair loop: wave w covers
// j in [w*256,(w+1)*256), 4 rows in registers, 16 exp chains (ILP).
// TAIL=0: LN0+beta+lrelu -> a0b bf16 [1024][296].  TAIL=1: LN1+head -> out.
// ---------------------------------------------------------------------------
template<int TAIL>
__global__ __launch_bounds__(256) void divln_kernel(
    const unsigned short* __restrict__ Mt, const float* __restrict__ h,
    const float* __restrict__ beta, const float* __restrict__ Wf,
    const float* __restrict__ bfv,
    unsigned short* __restrict__ a0b, float* __restrict__ out)
{
    __shared__ float Ms[2][1024 * 11];   // 90,112 B
    __shared__ float divP[4][4][10];     // [wave][row][k]

    const int t = threadIdx.x, lane = t & 63, w = t >> 6;
    const int r0 = blockIdx.x * 4;

    auto stage = [&](int buf, int k) {
        const unsigned short* src = Mt + (size_t)k * (1024 * 16);
        float* M = Ms[buf];
#pragma unroll
        for (int it = 0; it < 4; ++it) {
            const int j = it * 256 + t;
            const unsigned short* rp = src + (size_t)j * 16;
            const short8 v8 = *(const short8*)rp;
            const unsigned v2 = *(const unsigned*)(rp + 8);
            float* dst = M + j * 11;
#pragma unroll
            for (int d = 0; d < 8; ++d) dst[d] = bf2f((unsigned short)v8[d]);
            dst[8] = bf2f((unsigned short)(v2 & 0xffffu));
            dst[9] = bf2f((unsigned short)(v2 >> 16));
        }
    };

    stage(0, 0);
    __syncthreads();

    for (int k = 0; k < 10; ++k) {
        const int buf = k & 1;
        if (k + 1 < 10) stage(buf ^ 1, k + 1);

        const float* M = Ms[buf];
        float Mi[4][10];
#pragma unroll
        for (int rr = 0; rr < 4; ++rr)
#pragma unroll
            for (int d = 0; d < 10; ++d) Mi[rr][d] = M[(r0 + rr) * 11 + d];

        float acc0 = 0.f, acc1 = 0.f, acc2 = 0.f, acc3 = 0.f;
        const int jbase = w * 256;
#pragma unroll
        for (int jj = 0; jj < 4; ++jj) {
            const int j = jbase + jj * 64 + lane;
            const float* mp = M + j * 11;
            float m[10];
#pragma unroll
            for (int d = 0; d < 10; ++d) m[d] = mp[d];
            float l0 = 0.f, l1 = 0.f, l2 = 0.f, l3 = 0.f;
#pragma unroll
            for (int d = 0; d < 10; ++d) {
                l0 += fabsf(Mi[0][d] - m[d]);
                l1 += fabsf(Mi[1][d] - m[d]);
                l2 += fabsf(Mi[2][d] - m[d]);
                l3 += fabsf(Mi[3][d] - m[d]);
            }
            acc0 += __expf(-l0);
            acc1 += __expf(-l1);
            acc2 += __expf(-l2);
            acc3 += __expf(-l3);
        }
        float a[4] = {acc0, acc1, acc2, acc3};
#pragma unroll
        for (int rr = 0; rr < 4; ++rr) {
            float s = a[rr];
#pragma unroll
            for (int mm = 32; mm > 0; mm >>= 1) s += __shfl_xor(s, mm);
            if (lane == 0) divP[w][rr][k] = s;
        }
        __syncthreads();
    }

    // ---- fused LN tail: wave w handles row r0 + w ----
    const int row = r0 + w;
    float dv = 0.f;
    if (lane < 10)
        dv = divP[0][w][lane] + divP[1][w][lane] + divP[2][w][lane] + divP[3][w][lane];

    const float4 hv = ((const float4*)(h + (size_t)row * 256))[lane];
    float s = hv.x + hv.y + hv.z + hv.w + dv;
    float q = hv.x * hv.x + hv.y * hv.y + hv.z * hv.z + hv.w * hv.w + dv * dv;
#pragma unroll
    for (int m = 32; m > 0; m >>= 1) { s += __shfl_xor(s, m); q += __shfl_xor(q, m); }

    const float mean = s * (1.f / 266.f);
    const float var  = q * (1.f / 266.f) - mean * mean;
    const float inv  = rsqrtf(var + EPS);
    const float4 bv = ((const float4*)beta)[lane];

    if constexpr (TAIL == 0) {
        ushort4 o;
        o.x = f2bf(lrelu((hv.x - mean) * inv + bv.x));
        o.y = f2bf(lrelu((hv.y - mean) * inv + bv.y));
        o.z = f2bf(lrelu((hv.z - mean) * inv + bv.z));
        o.w = f2bf(lrelu((hv.w - mean) * inv + bv.w));
        *(ushort4*)&a0b[(size_t)row * 296 + lane * 4] = o;
        if (lane < 10)
            a0b[(size_t)row * 296 + 256 + lane] =
                f2bf(lrelu((dv - mean) * inv + beta[256 + lane]));
        else if (lane >= 16 && lane < 46)
            a0b[(size_t)row * 296 + 250 + lane] = 0;   // cols 266..295 zero
    } else {
        const float4 wf = ((const float4*)Wf)[lane];
        float d = lrelu((hv.x - mean) * inv + bv.x) * wf.x
                + lrelu((hv.y - mean) * inv + bv.y) * wf.y
                + lrelu((hv.z - mean) * inv + bv.z) * wf.z
                + lrelu((hv.w - mean) * inv + bv.w) * wf.w;
        if (lane < 10)
            d += lrelu((dv - mean) * inv + beta[256 + lane]) * Wf[256 + lane];
#pragma unroll
        for (int m = 32; m > 0; m >>= 1) d += __shfl_xor(d, m);
        if (lane == 0) out[row] = d + bfv[0];
    }
}

// ---------------------------------------------------------------------------
extern "C" void kernel_launch(void* const* d_in, const int* in_sizes, int n_in,
                              void* d_out, int out_size, void* d_ws, size_t ws_size,
                              hipStream_t stream)
{
    const float* x     = (const float*)d_in[0];
    const float* W0    = (const float*)d_in[1];
    const float* b0    = (const float*)d_in[2];
    const float* Wd0   = (const float*)d_in[3];
    const float* bd0   = (const float*)d_in[4];
    const float* beta0 = (const float*)d_in[5];
    const float* W1    = (const float*)d_in[6];
    const float* b1    = (const float*)d_in[7];
    const float* Wd1   = (const float*)d_in[8];
    const float* bd1   = (const float*)d_in[9];
    const float* beta1 = (const float*)d_in[10];
    const float* Wf    = (const float*)d_in[11];
    const float* bf    = (const float*)d_in[12];
    float* out = (float*)d_out;

    float* fws = (float*)d_ws;
    float* h0     = fws;                       // 1024*256
    float* h1     = h0 + 1024 * 256;           // 1024*256
    float* bcomb0 = h1 + 1024 * 256;           // 128
    float* bcomb1 = bcomb0 + 128;              // 128
    unsigned short* Wc0bT = (unsigned short*)(bcomb1 + 128);  // [128][512]
    unsigned short* Wc1bT = Wc0bT + 128 * 512;                // [128][296]
    unsigned short* a0b   = Wc1bT + 128 * 296;                // [1024][296]
    unsigned short* Mt0   = a0b + 1024 * 296;                 // [10][1024][16]
    unsigned short* Mt1   = Mt0 + 10 * 1024 * 16;             // [10][1024][16]

    dim3 blk(256);

    // N1: Wc (MFMA) + bcomb
    prep_kernel<<<dim3(102), blk, 0, stream>>>(
        W0, Wd0, W1, Wd1, b0, bd0, b1, bd1, Wc0bT, Wc1bT, bcomb0, bcomb1);

    // N2: h0 = x@W0+b0 || Mt0 = x@Wc0+bcomb0 (bf16)
    hm0_mfma<<<dim3(32, 12), blk, 0, stream>>>(
        x, W0, Wc0bT, b0, bcomb0, h0, Mt0);

    // N3: diversity 0 + fused LN0 -> a0b
    divln_kernel<0><<<dim3(256), blk, 0, stream>>>(
        Mt0, h0, beta0, nullptr, nullptr, a0b, nullptr);

    // N4: h1 = a0@W1+b1 || Mt1 = a0@Wc1+bcomb1 (bf16)
    hm1_mfma<<<dim3(32, 12), blk, 0, stream>>>(
        a0b, W1, Wc1bT, b1, bcomb1, h1, Mt1);

    // N5: diversity 1 + fused LN1+head -> out
    divln_kernel<1><<<dim3(256), blk, 0, stream>>>(
        Mt1, h1, beta1, Wf, bf, nullptr, out);
}

// Round 18
// 63.550 us; speedup vs baseline: 1.2995x; 1.2995x over previous
//
#include <hip/hip_runtime.h>

typedef __attribute__((ext_vector_type(8))) short short8;
typedef __attribute__((ext_vector_type(4))) float f32x4;

#define EPS   1e-3f
#define ALPHA 0.3f

#define MFMA(a, b, c) __builtin_amdgcn_mfma_f32_16x16x32_bf16((a), (b), (c), 0, 0, 0)

__device__ __forceinline__ unsigned short f2bf(float f) {
    unsigned u = __float_as_uint(f);
    unsigned r = u + 0x7FFFu + ((u >> 16) & 1u);
    return (unsigned short)(r >> 16);
}
__device__ __forceinline__ float lrelu(float v) { return v > 0.f ? v : ALPHA * v; }

// ---------------------------------------------------------------------------
// N1 prep (102 blocks), all-MFMA Wc:
//   bid 0..63 : Wc0bT [128c][512f] bf16 from W0@Wd0 (tile 32f x 32c).
//   bid 64..99: Wc1bT [128c][296f] bf16 from W1(a<266)@Wd1.
//   bid 100/101: bcomb = b@Wd + bd (128-wide, zero-padded).
// ---------------------------------------------------------------------------
__global__ __launch_bounds__(256) void prep_kernel(
    const float* __restrict__ W0, const float* __restrict__ Wd0,
    const float* __restrict__ W1, const float* __restrict__ Wd1,
    const float* __restrict__ b0, const float* __restrict__ bd0,
    const float* __restrict__ b1, const float* __restrict__ bd1,
    unsigned short* __restrict__ Wc0bT, unsigned short* __restrict__ Wc1bT,
    float* __restrict__ bcomb0, float* __restrict__ bcomb1)
{
    const int bid = blockIdx.x, t = threadIdx.x;
    if (bid < 100) {
        __shared__ unsigned short Ab[32][264];   // W rows (f-dim), k=256
        __shared__ unsigned short BbT[32][264];  // Wd^T rows (c-dim), k=256
        const float *Wsrc, *Wdsrc;
        unsigned short* Cdst;
        int ldc, ft, ct, arows;
        if (bid < 64) { ft = bid & 15; ct = bid >> 4; Wsrc = W0; Wdsrc = Wd0;
                        Cdst = Wc0bT; ldc = 512; arows = 512; }
        else { const int s = bid - 64; ft = s % 9; ct = s / 9;
               Wsrc = W1; Wdsrc = Wd1; Cdst = Wc1bT; ldc = 296; arows = 266; }

        {
            const int row = t >> 3, kc = t & 7;
            const int f = ft * 32 + row;
            if (f < arows) {
                const float* wp = Wsrc + (size_t)f * 256 + kc * 32;
#pragma unroll
                for (int i = 0; i < 8; ++i) {
                    const float4 v = ((const float4*)wp)[i];
                    Ab[row][kc * 32 + i * 4 + 0] = f2bf(v.x);
                    Ab[row][kc * 32 + i * 4 + 1] = f2bf(v.y);
                    Ab[row][kc * 32 + i * 4 + 2] = f2bf(v.z);
                    Ab[row][kc * 32 + i * 4 + 3] = f2bf(v.w);
                }
            } else {
#pragma unroll
                for (int i = 0; i < 8; ++i)
                    *(ushort4*)&Ab[row][kc * 32 + i * 4] = make_ushort4(0, 0, 0, 0);
            }
        }
        for (int idx = t; idx < 2048; idx += 256) {
            const int h = idx >> 3, c4 = idx & 7;
            const int cbase = ct * 32 + c4 * 4;
            float v[4];
            if (cbase + 3 < 100) {
                const float4 q = *(const float4*)&Wdsrc[(size_t)h * 100 + cbase];
                v[0] = q.x; v[1] = q.y; v[2] = q.z; v[3] = q.w;
            } else {
#pragma unroll
                for (int j = 0; j < 4; ++j)
                    v[j] = (cbase + j < 100) ? Wdsrc[(size_t)h * 100 + cbase + j] : 0.f;
            }
#pragma unroll
            for (int j = 0; j < 4; ++j) BbT[c4 * 4 + j][h] = f2bf(v[j]);
        }
        __syncthreads();

        const int lane = t & 63, w = t >> 6;
        const int cr = w & 1, fr = w >> 1, r = lane & 15, g = lane >> 4;
        const unsigned short* Ap = &BbT[cr * 16 + r][g * 8];
        const unsigned short* Bp = &Ab[fr * 16 + r][g * 8];
        f32x4 a0 = {0.f, 0.f, 0.f, 0.f}, a1 = {0.f, 0.f, 0.f, 0.f};
#pragma unroll
        for (int k0 = 0; k0 < 256; k0 += 64) {
            a0 = MFMA(*(const short8*)(Ap + k0),      *(const short8*)(Bp + k0),      a0);
            a1 = MFMA(*(const short8*)(Ap + k0 + 32), *(const short8*)(Bp + k0 + 32), a1);
        }
        const f32x4 acc = a0 + a1;
        const int crow = ct * 32 + cr * 16 + g * 4;
        const int fcol = ft * 32 + fr * 16 + r;
#pragma unroll
        for (int i = 0; i < 4; ++i)
            Cdst[(size_t)(crow + i) * ldc + fcol] = f2bf(acc[i]);
    } else {
        const float* bb = (bid == 100) ? b0 : b1;
        const float* Wd = (bid == 100) ? Wd0 : Wd1;
        const float* bd = (bid == 100) ? bd0 : bd1;
        float* o = (bid == 100) ? bcomb0 : bcomb1;
        if (t < 128) {
            float s = 0.f;
            if (t < 100) {
                s = bd[t];
                float s0 = 0.f, s1 = 0.f, s2 = 0.f, s3 = 0.f;
                for (int k = 0; k < 256; k += 4) {
                    s0 += bb[k]     * Wd[k * 100 + t];
                    s1 += bb[k + 1] * Wd[(k + 1) * 100 + t];
                    s2 += bb[k + 2] * Wd[(k + 2) * 100 + t];
                    s3 += bb[k + 3] * Wd[(k + 3) * 100 + t];
                }
                s += (s0 + s1) + (s2 + s3);
            }
            o[t] = s;
        }
    }
}

// ---------------------------------------------------------------------------
// N2 hm0: grid (32,12). yt<8: h0 = x@W0+b0; yt>=8: Mt0 = x@Wc0+bcomb0. K=512.
// ---------------------------------------------------------------------------
__global__ __launch_bounds__(256) void hm0_mfma(
    const float* __restrict__ x, const float* __restrict__ W0,
    const unsigned short* __restrict__ Wc0bT,
    const float* __restrict__ b0, const float* __restrict__ bcomb0,
    float* __restrict__ h0, float* __restrict__ Mt0)
{
    __shared__ unsigned short At[32][520];
    __shared__ unsigned short Bt[32][520];

    const int t = threadIdx.x, xt = blockIdx.x, yt = blockIdx.y;

    {
        const int row = t >> 3, kc = t & 7;
        const float* xp = x + (size_t)(xt * 32 + row) * 512 + kc * 64;
#pragma unroll
        for (int i = 0; i < 8; ++i) {
            const float4 lo = ((const float4*)xp)[i * 2];
            const float4 hi = ((const float4*)xp)[i * 2 + 1];
            short8 p;
            p[0] = f2bf(lo.x); p[1] = f2bf(lo.y); p[2] = f2bf(lo.z); p[3] = f2bf(lo.w);
            p[4] = f2bf(hi.x); p[5] = f2bf(hi.y); p[6] = f2bf(hi.z); p[7] = f2bf(hi.w);
            *(short8*)&At[row][kc * 64 + i * 8] = p;
        }
    }
    if (yt < 8) {
        const int kc = t >> 5, n = t & 31, col0 = yt * 32;
        for (int kk = 0; kk < 64; kk += 2) {
            const int k = kc * 64 + kk;
            const float a = W0[(size_t)k * 256 + col0 + n];
            const float b = W0[(size_t)(k + 1) * 256 + col0 + n];
            const unsigned pk = (unsigned)f2bf(a) | ((unsigned)f2bf(b) << 16);
            *(unsigned*)&Bt[n][k] = pk;
        }
    } else {
        const int c = t >> 3, kc = t & 7;
        const unsigned short* bp = Wc0bT + (size_t)((yt - 8) * 32 + c) * 512 + kc * 64;
#pragma unroll
        for (int i = 0; i < 8; ++i)
            *(short8*)&Bt[c][kc * 64 + i * 8] = ((const short8*)bp)[i];
    }
    __syncthreads();

    const int lane = t & 63, w = t >> 6;
    const int wr = w >> 1, wn = w & 1, r = lane & 15, g = lane >> 4;
    const int lrA = wr * 16 + r, lrB = wn * 16 + r;
    f32x4 a0 = {0.f, 0.f, 0.f, 0.f}, a1 = {0.f, 0.f, 0.f, 0.f};
#pragma unroll
    for (int k0 = 0; k0 < 512; k0 += 64) {
        a0 = MFMA(*(const short8*)&At[lrA][k0 + g * 8],
                  *(const short8*)&Bt[lrB][k0 + g * 8], a0);
        a1 = MFMA(*(const short8*)&At[lrA][k0 + 32 + g * 8],
                  *(const short8*)&Bt[lrB][k0 + 32 + g * 8], a1);
    }
    const f32x4 acc = a0 + a1;
    const int orow0 = xt * 32 + wr * 16 + g * 4;

    if (yt < 8) {
        const int bcol = yt * 32 + wn * 16 + r;
        const float bv = b0[bcol];
#pragma unroll
        for (int i = 0; i < 4; ++i)
            h0[(size_t)(orow0 + i) * 256 + bcol] = acc[i] + bv;
    } else {
        const int c = (yt - 8) * 32 + wn * 16 + r;
        if (c < 100) {
            const int kq = c / 10, d = c - kq * 10;
            const float bv = bcomb0[c];
            float* dst = Mt0 + (size_t)kq * (1024 * 16) + (size_t)orow0 * 16 + d;
#pragma unroll
            for (int i = 0; i < 4; ++i) dst[i * 16] = acc[i] + bv;
        }
    }
}

// ---------------------------------------------------------------------------
// N5 hm1: grid (32,12). A = a0b bf16 [1024][296]. yt<8: h1; yt>=8: Mt1. K=288.
// ---------------------------------------------------------------------------
__global__ __launch_bounds__(256) void hm1_mfma(
    const unsigned short* __restrict__ a0b, const float* __restrict__ W1,
    const unsigned short* __restrict__ Wc1bT,
    const float* __restrict__ b1, const float* __restrict__ bcomb1,
    float* __restrict__ h1, float* __restrict__ Mt1)
{
    __shared__ unsigned short At[32][296];
    __shared__ unsigned short Bt[32][296];

    const int t = threadIdx.x, xt = blockIdx.x, yt = blockIdx.y;

    {
        const int row = t >> 3, kc = t & 7;
        const unsigned short* ap = a0b + (size_t)(xt * 32 + row) * 296;
        for (int i = kc; i < 37; i += 8)
            *(short8*)&At[row][i * 8] = ((const short8*)ap)[i];
    }
    if (yt < 8) {
        const int kc = t >> 5, n = t & 31, col0 = yt * 32;
        const int kkEnd = (kc == 7) ? 44 : 36;
        for (int kk = 0; kk < kkEnd; kk += 2) {
            const int k = kc * 36 + kk;
            const float a = (k < 266)     ? W1[(size_t)k * 256 + col0 + n] : 0.f;
            const float b = (k + 1 < 266) ? W1[(size_t)(k + 1) * 256 + col0 + n] : 0.f;
            const unsigned pk = (unsigned)f2bf(a) | ((unsigned)f2bf(b) << 16);
            *(unsigned*)&Bt[n][k] = pk;
        }
    } else {
        const int c = t >> 3, kc = t & 7;
        const unsigned short* bp = Wc1bT + (size_t)((yt - 8) * 32 + c) * 296;
        for (int i = kc; i < 37; i += 8)
            *(short8*)&Bt[c][i * 8] = ((const short8*)bp)[i];
    }
    __syncthreads();

    const int lane = t & 63, w = t >> 6;
    const int wr = w >> 1, wn = w & 1, r = lane & 15, g = lane >> 4;
    const int lrA = wr * 16 + r, lrB = wn * 16 + r;
    f32x4 a0 = {0.f, 0.f, 0.f, 0.f}, a1 = {0.f, 0.f, 0.f, 0.f};
#pragma unroll
    for (int k0 = 0; k0 < 256; k0 += 64) {
        a0 = MFMA(*(const short8*)&At[lrA][k0 + g * 8],
                  *(const short8*)&Bt[lrB][k0 + g * 8], a0);
        a1 = MFMA(*(const short8*)&At[lrA][k0 + 32 + g * 8],
                  *(const short8*)&Bt[lrB][k0 + 32 + g * 8], a1);
    }
    a0 = MFMA(*(const short8*)&At[lrA][256 + g * 8],
              *(const short8*)&Bt[lrB][256 + g * 8], a0);
    const f32x4 acc = a0 + a1;
    const int orow0 = xt * 32 + wr * 16 + g * 4;

    if (yt < 8) {
        const int bcol = yt * 32 + wn * 16 + r;
        const float bv = b1[bcol];
#pragma unroll
        for (int i = 0; i < 4; ++i)
            h1[(size_t)(orow0 + i) * 256 + bcol] = acc[i] + bv;
    } else {
        const int c = (yt - 8) * 32 + wn * 16 + r;
        if (c < 100) {
            const int kq = c / 10, d = c - kq * 10;
            const float bv = bcomb1[c];
            float* dst = Mt1 + (size_t)kq * (1024 * 16) + (size_t)orow0 * 16 + d;
#pragma unroll
            for (int i = 0; i < 4; ++i) dst[i * 16] = acc[i] + bv;
        }
    }
}

// ---------------------------------------------------------------------------
// N3/N6 diversity: grid (32,10). Mt slice [1024][16] staged coalesced.
// Pair loop unrolled x4 for ILP.
// ---------------------------------------------------------------------------
__global__ __launch_bounds__(256) void diversity_kernel(
    const float* __restrict__ Mt, float* __restrict__ divOut)
{
    __shared__ float Ms[1024 * 16];
    __shared__ float red[256];

    const int t = threadIdx.x;
    const float* src = Mt + (size_t)blockIdx.y * (1024 * 16);
    for (int i = t; i < 1024 * 4; i += 256)
        ((float4*)Ms)[i] = ((const float4*)src)[i];
    __syncthreads();

    const int il = t & 31, jc = t >> 5;
    const int i = blockIdx.x * 32 + il;

    const float4 m0 = *(const float4*)&Ms[i * 16];
    const float4 m1 = *(const float4*)&Ms[i * 16 + 4];
    const float2 m2 = *(const float2*)&Ms[i * 16 + 8];

    float acc = 0.f;
    const int jB = jc * 128;
#pragma unroll 4
    for (int j = jB; j < jB + 128; ++j) {
        const float4 v0 = *(const float4*)&Ms[j * 16];
        const float4 v1 = *(const float4*)&Ms[j * 16 + 4];
        const float2 v2 = *(const float2*)&Ms[j * 16 + 8];
        float l1 = fabsf(m0.x - v0.x) + fabsf(m0.y - v0.y)
                 + fabsf(m0.z - v0.z) + fabsf(m0.w - v0.w)
                 + fabsf(m1.x - v1.x) + fabsf(m1.y - v1.y)
                 + fabsf(m1.z - v1.z) + fabsf(m1.w - v1.w)
                 + fabsf(m2.x - v2.x) + fabsf(m2.y - v2.y);
        acc += __expf(-l1);
    }

    red[t] = acc;
    __syncthreads();
    if (t < 32) {
        float s = 0.f;
#pragma unroll
        for (int c = 0; c < 8; ++c) s += red[c * 32 + t];
        divOut[(size_t)(blockIdx.x * 32 + t) * 10 + blockIdx.y] = s;
    }
}

// ---------------------------------------------------------------------------
// N4 ln0: 256 blocks x 4 waves; one row per wave. LN + lrelu -> a0b [1024][296].
// ---------------------------------------------------------------------------
__global__ __launch_bounds__(256) void ln0_kernel(
    const float* __restrict__ h0, const float* __restrict__ div0,
    const float* __restrict__ beta0, unsigned short* __restrict__ a0b)
{
    const int t = threadIdx.x, lane = t & 63;
    const int row = blockIdx.x * 4 + (t >> 6);

    const float4 hv = ((const float4*)(h0 + (size_t)row * 256))[lane];
    const float dv = (lane < 10) ? div0[(size_t)row * 10 + lane] : 0.f;

    float s = hv.x + hv.y + hv.z + hv.w + dv;
    float q = hv.x * hv.x + hv.y * hv.y + hv.z * hv.z + hv.w * hv.w + dv * dv;
#pragma unroll
    for (int m = 32; m > 0; m >>= 1) { s += __shfl_xor(s, m); q += __shfl_xor(q, m); }

    const float mean = s * (1.f / 266.f);
    const float var  = q * (1.f / 266.f) - mean * mean;
    const float inv  = rsqrtf(var + EPS);

    const float4 bv = ((const float4*)beta0)[lane];
    ushort4 o;
    o.x = f2bf(lrelu((hv.x - mean) * inv + bv.x));
    o.y = f2bf(lrelu((hv.y - mean) * inv + bv.y));
    o.z = f2bf(lrelu((hv.z - mean) * inv + bv.z));
    o.w = f2bf(lrelu((hv.w - mean) * inv + bv.w));
    *(ushort4*)&a0b[(size_t)row * 296 + lane * 4] = o;

    if (lane < 10)
        a0b[(size_t)row * 296 + 256 + lane] = f2bf(lrelu((dv - mean) * inv + beta0[256 + lane]));
    else if (lane >= 16 && lane < 46)
        a0b[(size_t)row * 296 + 250 + lane] = 0;   // cols 266..295 zero
}

// ---------------------------------------------------------------------------
// N7 ln_final: 256 blocks x 4 waves; LN + lrelu + dot(Wf) + bf.
// ---------------------------------------------------------------------------
__global__ __launch_bounds__(256) void ln_final(
    const float* __restrict__ h1, const float* __restrict__ div1,
    const float* __restrict__ beta1, const float* __restrict__ Wf,
    const float* __restrict__ bf, float* __restrict__ out)
{
    const int t = threadIdx.x, lane = t & 63;
    const int row = blockIdx.x * 4 + (t >> 6);

    const float4 hv = ((const float4*)(h1 + (size_t)row * 256))[lane];
    const float dv = (lane < 10) ? div1[(size_t)row * 10 + lane] : 0.f;

    float s = hv.x + hv.y + hv.z + hv.w + dv;
    float q = hv.x * hv.x + hv.y * hv.y + hv.z * hv.z + hv.w * hv.w + dv * dv;
#pragma unroll
    for (int m = 32; m > 0; m >>= 1) { s += __shfl_xor(s, m); q += __shfl_xor(q, m); }

    const float mean = s * (1.f / 266.f);
    const float var  = q * (1.f / 266.f) - mean * mean;
    const float inv  = rsqrtf(var + EPS);

    const float4 bv = ((const float4*)beta1)[lane];
    const float4 wf = ((const float4*)Wf)[lane];
    float d = lrelu((hv.x - mean) * inv + bv.x) * wf.x
            + lrelu((hv.y - mean) * inv + bv.y) * wf.y
            + lrelu((hv.z - mean) * inv + bv.z) * wf.z
            + lrelu((hv.w - mean) * inv + bv.w) * wf.w;
    if (lane < 10)
        d += lrelu((dv - mean) * inv + beta1[256 + lane]) * Wf[256 + lane];
#pragma unroll
    for (int m = 32; m > 0; m >>= 1) d += __shfl_xor(d, m);
    if (lane == 0) out[row] = d + bf[0];
}

// ---------------------------------------------------------------------------
extern "C" void kernel_launch(void* const* d_in, const int* in_sizes, int n_in,
                              void* d_out, int out_size, void* d_ws, size_t ws_size,
                              hipStream_t stream)
{
    const float* x     = (const float*)d_in[0];
    const float* W0    = (const float*)d_in[1];
    const float* b0    = (const float*)d_in[2];
    const float* Wd0   = (const float*)d_in[3];
    const float* bd0   = (const float*)d_in[4];
    const float* beta0 = (const float*)d_in[5];
    const float* W1    = (const float*)d_in[6];
    const float* b1    = (const float*)d_in[7];
    const float* Wd1   = (const float*)d_in[8];
    const float* bd1   = (const float*)d_in[9];
    const float* beta1 = (const float*)d_in[10];
    const float* Wf    = (const float*)d_in[11];
    const float* bf    = (const float*)d_in[12];
    float* out = (float*)d_out;

    float* fws = (float*)d_ws;
    float* h0     = fws;                       // 1024*256
    float* h1     = h0 + 1024 * 256;           // 1024*256
    float* Mt0    = h1 + 1024 * 256;           // 10*1024*16
    float* Mt1    = Mt0 + 10 * 1024 * 16;      // 10*1024*16
    float* div0   = Mt1 + 10 * 1024 * 16;      // 1024*10
    float* div1   = div0 + 1024 * 10;          // 1024*10
    float* bcomb0 = div1 + 1024 * 10;          // 128
    float* bcomb1 = bcomb0 + 128;              // 128
    unsigned short* Wc0bT = (unsigned short*)(bcomb1 + 128);  // [128][512]
    unsigned short* Wc1bT = Wc0bT + 128 * 512;                // [128][296]
    unsigned short* a0b   = Wc1bT + 128 * 296;                // [1024][296]

    dim3 blk(256);

    prep_kernel<<<dim3(102), blk, 0, stream>>>(
        W0, Wd0, W1, Wd1, b0, bd0, b1, bd1, Wc0bT, Wc1bT, bcomb0, bcomb1);

    hm0_mfma<<<dim3(32, 12), blk, 0, stream>>>(
        x, W0, Wc0bT, b0, bcomb0, h0, Mt0);

    diversity_kernel<<<dim3(32, 10), blk, 0, stream>>>(Mt0, div0);

    ln0_kernel<<<dim3(256), blk, 0, stream>>>(h0, div0, beta0, a0b);

    hm1_mfma<<<dim3(32, 12), blk, 0, stream>>>(
        a0b, W1, Wc1bT, b1, bcomb1, h1, Mt1);

    diversity_kernel<<<dim3(32, 10), blk, 0, stream>>>(Mt1, div1);

    ln_final<<<dim3(256), blk, 0, stream>>>(h1, div1, beta1, Wf, bf, out);
}

// Round 19
// 61.478 us; speedup vs baseline: 1.3434x; 1.0337x over previous
//
#include <hip/hip_runtime.h>

typedef __attribute__((ext_vector_type(8))) short short8;
typedef __attribute__((ext_vector_type(4))) float f32x4;

#define EPS   1e-3f
#define ALPHA 0.3f

#define MFMA(a, b, c) __builtin_amdgcn_mfma_f32_16x16x32_bf16((a), (b), (c), 0, 0, 0)

__device__ __forceinline__ unsigned short f2bf(float f) {
    unsigned u = __float_as_uint(f);
    unsigned r = u + 0x7FFFu + ((u >> 16) & 1u);
    return (unsigned short)(r >> 16);
}
__device__ __forceinline__ float lrelu(float v) { return v > 0.f ? v : ALPHA * v; }

// ---------------------------------------------------------------------------
// N1 prep (102 blocks), all-MFMA Wc:
//   bid 0..63 : Wc0bT [128c][512f] bf16 from W0@Wd0 (tile 32f x 32c).
//   bid 64..99: Wc1bT [128c][296f] bf16 from W1(a<266)@Wd1.
//   bid 100/101: bcomb = b@Wd + bd (128-wide, zero-padded).
// ---------------------------------------------------------------------------
__global__ __launch_bounds__(256) void prep_kernel(
    const float* __restrict__ W0, const float* __restrict__ Wd0,
    const float* __restrict__ W1, const float* __restrict__ Wd1,
    const float* __restrict__ b0, const float* __restrict__ bd0,
    const float* __restrict__ b1, const float* __restrict__ bd1,
    unsigned short* __restrict__ Wc0bT, unsigned short* __restrict__ Wc1bT,
    float* __restrict__ bcomb0, float* __restrict__ bcomb1)
{
    const int bid = blockIdx.x, t = threadIdx.x;
    if (bid < 100) {
        __shared__ unsigned short Ab[32][264];   // W rows (f-dim), k=256
        __shared__ unsigned short BbT[32][264];  // Wd^T rows (c-dim), k=256
        const float *Wsrc, *Wdsrc;
        unsigned short* Cdst;
        int ldc, ft, ct, arows;
        if (bid < 64) { ft = bid & 15; ct = bid >> 4; Wsrc = W0; Wdsrc = Wd0;
                        Cdst = Wc0bT; ldc = 512; arows = 512; }
        else { const int s = bid - 64; ft = s % 9; ct = s / 9;
               Wsrc = W1; Wdsrc = Wd1; Cdst = Wc1bT; ldc = 296; arows = 266; }

        {
            const int row = t >> 3, kc = t & 7;
            const int f = ft * 32 + row;
            if (f < arows) {
                const float* wp = Wsrc + (size_t)f * 256 + kc * 32;
#pragma unroll
                for (int i = 0; i < 8; ++i) {
                    const float4 v = ((const float4*)wp)[i];
                    Ab[row][kc * 32 + i * 4 + 0] = f2bf(v.x);
                    Ab[row][kc * 32 + i * 4 + 1] = f2bf(v.y);
                    Ab[row][kc * 32 + i * 4 + 2] = f2bf(v.z);
                    Ab[row][kc * 32 + i * 4 + 3] = f2bf(v.w);
                }
            } else {
#pragma unroll
                for (int i = 0; i < 8; ++i)
                    *(ushort4*)&Ab[row][kc * 32 + i * 4] = make_ushort4(0, 0, 0, 0);
            }
        }
        for (int idx = t; idx < 2048; idx += 256) {
            const int h = idx >> 3, c4 = idx & 7;
            const int cbase = ct * 32 + c4 * 4;
            float v[4];
            if (cbase + 3 < 100) {
                const float4 q = *(const float4*)&Wdsrc[(size_t)h * 100 + cbase];
                v[0] = q.x; v[1] = q.y; v[2] = q.z; v[3] = q.w;
            } else {
#pragma unroll
                for (int j = 0; j < 4; ++j)
                    v[j] = (cbase + j < 100) ? Wdsrc[(size_t)h * 100 + cbase + j] : 0.f;
            }
#pragma unroll
            for (int j = 0; j < 4; ++j) BbT[c4 * 4 + j][h] = f2bf(v[j]);
        }
        __syncthreads();

        const int lane = t & 63, w = t >> 6;
        const int cr = w & 1, fr = w >> 1, r = lane & 15, g = lane >> 4;
        const unsigned short* Ap = &BbT[cr * 16 + r][g * 8];
        const unsigned short* Bp = &Ab[fr * 16 + r][g * 8];
        f32x4 a0 = {0.f, 0.f, 0.f, 0.f}, a1 = {0.f, 0.f, 0.f, 0.f};
#pragma unroll
        for (int k0 = 0; k0 < 256; k0 += 64) {
            a0 = MFMA(*(const short8*)(Ap + k0),      *(const short8*)(Bp + k0),      a0);
            a1 = MFMA(*(const short8*)(Ap + k0 + 32), *(const short8*)(Bp + k0 + 32), a1);
        }
        const f32x4 acc = a0 + a1;
        const int crow = ct * 32 + cr * 16 + g * 4;
        const int fcol = ft * 32 + fr * 16 + r;
#pragma unroll
        for (int i = 0; i < 4; ++i)
            Cdst[(size_t)(crow + i) * ldc + fcol] = f2bf(acc[i]);
    } else {
        const float* bb = (bid == 100) ? b0 : b1;
        const float* Wd = (bid == 100) ? Wd0 : Wd1;
        const float* bd = (bid == 100) ? bd0 : bd1;
        float* o = (bid == 100) ? bcomb0 : bcomb1;
        if (t < 128) {
            float s = 0.f;
            if (t < 100) {
                s = bd[t];
                float s0 = 0.f, s1 = 0.f, s2 = 0.f, s3 = 0.f;
                for (int k = 0; k < 256; k += 4) {
                    s0 += bb[k]     * Wd[k * 100 + t];
                    s1 += bb[k + 1] * Wd[(k + 1) * 100 + t];
                    s2 += bb[k + 2] * Wd[(k + 2) * 100 + t];
                    s3 += bb[k + 3] * Wd[(k + 3) * 100 + t];
                }
                s += (s0 + s1) + (s2 + s3);
            }
            o[t] = s;
        }
    }
}

// ---------------------------------------------------------------------------
// N2 hm0: grid (32,12). yt<8: h0 = x@W0+b0; yt>=8: Mt0 = x@Wc0+bcomb0. K=512.
// B-stage for yt<8 now float4-coalesced (16 rounds) instead of 128 scalars.
// ---------------------------------------------------------------------------
__global__ __launch_bounds__(256) void hm0_mfma(
    const float* __restrict__ x, const float* __restrict__ W0,
    const unsigned short* __restrict__ Wc0bT,
    const float* __restrict__ b0, const float* __restrict__ bcomb0,
    float* __restrict__ h0, float* __restrict__ Mt0)
{
    __shared__ unsigned short At[32][520];
    __shared__ unsigned short Bt[32][520];

    const int t = threadIdx.x, xt = blockIdx.x, yt = blockIdx.y;

    {
        const int row = t >> 3, kc = t & 7;
        const float* xp = x + (size_t)(xt * 32 + row) * 512 + kc * 64;
#pragma unroll
        for (int i = 0; i < 8; ++i) {
            const float4 lo = ((const float4*)xp)[i * 2];
            const float4 hi = ((const float4*)xp)[i * 2 + 1];
            short8 p;
            p[0] = f2bf(lo.x); p[1] = f2bf(lo.y); p[2] = f2bf(lo.z); p[3] = f2bf(lo.w);
            p[4] = f2bf(hi.x); p[5] = f2bf(hi.y); p[6] = f2bf(hi.z); p[7] = f2bf(hi.w);
            *(short8*)&At[row][kc * 64 + i * 8] = p;
        }
    }
    if (yt < 8) {
        // float4-coalesced transpose staging (R13-proven pattern)
        const int kr = t >> 3, nf = t & 7;
#pragma unroll
        for (int rnd = 0; rnd < 16; ++rnd) {
            const int k = kr + rnd * 32;
            const float4 v = *(const float4*)&W0[(size_t)k * 256 + yt * 32 + nf * 4];
            Bt[nf * 4 + 0][k] = f2bf(v.x);
            Bt[nf * 4 + 1][k] = f2bf(v.y);
            Bt[nf * 4 + 2][k] = f2bf(v.z);
            Bt[nf * 4 + 3][k] = f2bf(v.w);
        }
    } else {
        const int c = t >> 3, kc = t & 7;
        const unsigned short* bp = Wc0bT + (size_t)((yt - 8) * 32 + c) * 512 + kc * 64;
#pragma unroll
        for (int i = 0; i < 8; ++i)
            *(short8*)&Bt[c][kc * 64 + i * 8] = ((const short8*)bp)[i];
    }
    __syncthreads();

    const int lane = t & 63, w = t >> 6;
    const int wr = w >> 1, wn = w & 1, r = lane & 15, g = lane >> 4;
    const int lrA = wr * 16 + r, lrB = wn * 16 + r;
    f32x4 a0 = {0.f, 0.f, 0.f, 0.f}, a1 = {0.f, 0.f, 0.f, 0.f};
#pragma unroll
    for (int k0 = 0; k0 < 512; k0 += 64) {
        a0 = MFMA(*(const short8*)&At[lrA][k0 + g * 8],
                  *(const short8*)&Bt[lrB][k0 + g * 8], a0);
        a1 = MFMA(*(const short8*)&At[lrA][k0 + 32 + g * 8],
                  *(const short8*)&Bt[lrB][k0 + 32 + g * 8], a1);
    }
    const f32x4 acc = a0 + a1;
    const int orow0 = xt * 32 + wr * 16 + g * 4;

    if (yt < 8) {
        const int bcol = yt * 32 + wn * 16 + r;
        const float bv = b0[bcol];
#pragma unroll
        for (int i = 0; i < 4; ++i)
            h0[(size_t)(orow0 + i) * 256 + bcol] = acc[i] + bv;
    } else {
        const int c = (yt - 8) * 32 + wn * 16 + r;
        if (c < 100) {
            const int kq = c / 10, d = c - kq * 10;
            const float bv = bcomb0[c];
            float* dst = Mt0 + (size_t)kq * (1024 * 16) + (size_t)orow0 * 16 + d;
#pragma unroll
            for (int i = 0; i < 4; ++i) dst[i * 16] = acc[i] + bv;
        }
    }
}

// ---------------------------------------------------------------------------
// N5 hm1: grid (32,12). A = a0b bf16 [1024][296]. yt<8: h1; yt>=8: Mt1. K=288.
// B-stage for yt<8 now float4-coalesced (9 rounds, k<266 zero-guard).
// ---------------------------------------------------------------------------
__global__ __launch_bounds__(256) void hm1_mfma(
    const unsigned short* __restrict__ a0b, const float* __restrict__ W1,
    const unsigned short* __restrict__ Wc1bT,
    const float* __restrict__ b1, const float* __restrict__ bcomb1,
    float* __restrict__ h1, float* __restrict__ Mt1)
{
    __shared__ unsigned short At[32][296];
    __shared__ unsigned short Bt[32][296];

    const int t = threadIdx.x, xt = blockIdx.x, yt = blockIdx.y;

    {
        const int row = t >> 3, kc = t & 7;
        const unsigned short* ap = a0b + (size_t)(xt * 32 + row) * 296;
        for (int i = kc; i < 37; i += 8)
            *(short8*)&At[row][i * 8] = ((const short8*)ap)[i];
    }
    if (yt < 8) {
        // float4-coalesced transpose staging, rows >= 266 zero (K padded 288)
        const int kr = t >> 3, nf = t & 7;
#pragma unroll
        for (int rnd = 0; rnd < 9; ++rnd) {
            const int k = kr + rnd * 32;
            float4 v = make_float4(0.f, 0.f, 0.f, 0.f);
            if (k < 266) v = *(const float4*)&W1[(size_t)k * 256 + yt * 32 + nf * 4];
            Bt[nf * 4 + 0][k] = f2bf(v.x);
            Bt[nf * 4 + 1][k] = f2bf(v.y);
            Bt[nf * 4 + 2][k] = f2bf(v.z);
            Bt[nf * 4 + 3][k] = f2bf(v.w);
        }
    } else {
        const int c = t >> 3, kc = t & 7;
        const unsigned short* bp = Wc1bT + (size_t)((yt - 8) * 32 + c) * 296;
        for (int i = kc; i < 37; i += 8)
            *(short8*)&Bt[c][i * 8] = ((const short8*)bp)[i];
    }
    __syncthreads();

    const int lane = t & 63, w = t >> 6;
    const int wr = w >> 1, wn = w & 1, r = lane & 15, g = lane >> 4;
    const int lrA = wr * 16 + r, lrB = wn * 16 + r;
    f32x4 a0 = {0.f, 0.f, 0.f, 0.f}, a1 = {0.f, 0.f, 0.f, 0.f};
#pragma unroll
    for (int k0 = 0; k0 < 256; k0 += 64) {
        a0 = MFMA(*(const short8*)&At[lrA][k0 + g * 8],
                  *(const short8*)&Bt[lrB][k0 + g * 8], a0);
        a1 = MFMA(*(const short8*)&At[lrA][k0 + 32 + g * 8],
                  *(const short8*)&Bt[lrB][k0 + 32 + g * 8], a1);
    }
    a0 = MFMA(*(const short8*)&At[lrA][256 + g * 8],
              *(const short8*)&Bt[lrB][256 + g * 8], a0);
    const f32x4 acc = a0 + a1;
    const int orow0 = xt * 32 + wr * 16 + g * 4;

    if (yt < 8) {
        const int bcol = yt * 32 + wn * 16 + r;
        const float bv = b1[bcol];
#pragma unroll
        for (int i = 0; i < 4; ++i)
            h1[(size_t)(orow0 + i) * 256 + bcol] = acc[i] + bv;
    } else {
        const int c = (yt - 8) * 32 + wn * 16 + r;
        if (c < 100) {
            const int kq = c / 10, d = c - kq * 10;
            const float bv = bcomb1[c];
            float* dst = Mt1 + (size_t)kq * (1024 * 16) + (size_t)orow0 * 16 + d;
#pragma unroll
            for (int i = 0; i < 4; ++i) dst[i * 16] = acc[i] + bv;
        }
    }
}

// ---------------------------------------------------------------------------
// N3/N6 diversity: grid (32,10). Mt slice [1024][16] staged coalesced.
// Pair loop unrolled x4 for ILP.
// ---------------------------------------------------------------------------
__global__ __launch_bounds__(256) void diversity_kernel(
    const float* __restrict__ Mt, float* __restrict__ divOut)
{
    __shared__ float Ms[1024 * 16];
    __shared__ float red[256];

    const int t = threadIdx.x;
    const float* src = Mt + (size_t)blockIdx.y * (1024 * 16);
    for (int i = t; i < 1024 * 4; i += 256)
        ((float4*)Ms)[i] = ((const float4*)src)[i];
    __syncthreads();

    const int il = t & 31, jc = t >> 5;
    const int i = blockIdx.x * 32 + il;

    const float4 m0 = *(const float4*)&Ms[i * 16];
    const float4 m1 = *(const float4*)&Ms[i * 16 + 4];
    const float2 m2 = *(const float2*)&Ms[i * 16 + 8];

    float acc = 0.f;
    const int jB = jc * 128;
#pragma unroll 4
    for (int j = jB; j < jB + 128; ++j) {
        const float4 v0 = *(const float4*)&Ms[j * 16];
        const float4 v1 = *(const float4*)&Ms[j * 16 + 4];
        const float2 v2 = *(const float2*)&Ms[j * 16 + 8];
        float l1 = fabsf(m0.x - v0.x) + fabsf(m0.y - v0.y)
                 + fabsf(m0.z - v0.z) + fabsf(m0.w - v0.w)
                 + fabsf(m1.x - v1.x) + fabsf(m1.y - v1.y)
                 + fabsf(m1.z - v1.z) + fabsf(m1.w - v1.w)
                 + fabsf(m2.x - v2.x) + fabsf(m2.y - v2.y);
        acc += __expf(-l1);
    }

    red[t] = acc;
    __syncthreads();
    if (t < 32) {
        float s = 0.f;
#pragma unroll
        for (int c = 0; c < 8; ++c) s += red[c * 32 + t];
        divOut[(size_t)(blockIdx.x * 32 + t) * 10 + blockIdx.y] = s;
    }
}

// ---------------------------------------------------------------------------
// N4 ln0: 256 blocks x 4 waves; one row per wave. LN + lrelu -> a0b [1024][296].
// ---------------------------------------------------------------------------
__global__ __launch_bounds__(256) void ln0_kernel(
    const float* __restrict__ h0, const float* __restrict__ div0,
    const float* __restrict__ beta0, unsigned short* __restrict__ a0b)
{
    const int t = threadIdx.x, lane = t & 63;
    const int row = blockIdx.x * 4 + (t >> 6);

    const float4 hv = ((const float4*)(h0 + (size_t)row * 256))[lane];
    const float dv = (lane < 10) ? div0[(size_t)row * 10 + lane] : 0.f;

    float s = hv.x + hv.y + hv.z + hv.w + dv;
    float q = hv.x * hv.x + hv.y * hv.y + hv.z * hv.z + hv.w * hv.w + dv * dv;
#pragma unroll
    for (int m = 32; m > 0; m >>= 1) { s += __shfl_xor(s, m); q += __shfl_xor(q, m); }

    const float mean = s * (1.f / 266.f);
    const float var  = q * (1.f / 266.f) - mean * mean;
    const float inv  = rsqrtf(var + EPS);

    const float4 bv = ((const float4*)beta0)[lane];
    ushort4 o;
    o.x = f2bf(lrelu((hv.x - mean) * inv + bv.x));
    o.y = f2bf(lrelu((hv.y - mean) * inv + bv.y));
    o.z = f2bf(lrelu((hv.z - mean) * inv + bv.z));
    o.w = f2bf(lrelu((hv.w - mean) * inv + bv.w));
    *(ushort4*)&a0b[(size_t)row * 296 + lane * 4] = o;

    if (lane < 10)
        a0b[(size_t)row * 296 + 256 + lane] = f2bf(lrelu((dv - mean) * inv + beta0[256 + lane]));
    else if (lane >= 16 && lane < 46)
        a0b[(size_t)row * 296 + 250 + lane] = 0;   // cols 266..295 zero
}

// ---------------------------------------------------------------------------
// N7 ln_final: 256 blocks x 4 waves; LN + lrelu + dot(Wf) + bf.
// ---------------------------------------------------------------------------
__global__ __launch_bounds__(256) void ln_final(
    const float* __restrict__ h1, const float* __restrict__ div1,
    const float* __restrict__ beta1, const float* __restrict__ Wf,
    const float* __restrict__ bf, float* __restrict__ out)
{
    const int t = threadIdx.x, lane = t & 63;
    const int row = blockIdx.x * 4 + (t >> 6);

    const float4 hv = ((const float4*)(h1 + (size_t)row * 256))[lane];
    const float dv = (lane < 10) ? div1[(size_t)row * 10 + lane] : 0.f;

    float s = hv.x + hv.y + hv.z + hv.w + dv;
    float q = hv.x * hv.x + hv.y * hv.y + hv.z * hv.z + hv.w * hv.w + dv * dv;
#pragma unroll
    for (int m = 32; m > 0; m >>= 1) { s += __shfl_xor(s, m); q += __shfl_xor(q, m); }

    const float mean = s * (1.f / 266.f);
    const float var  = q * (1.f / 266.f) - mean * mean;
    const float inv  = rsqrtf(var + EPS);

    const float4 bv = ((const float4*)beta1)[lane];
    const float4 wf = ((const float4*)Wf)[lane];
    float d = lrelu((hv.x - mean) * inv + bv.x) * wf.x
            + lrelu((hv.y - mean) * inv + bv.y) * wf.y
            + lrelu((hv.z - mean) * inv + bv.z) * wf.z
            + lrelu((hv.w - mean) * inv + bv.w) * wf.w;
    if (lane < 10)
        d += lrelu((dv - mean) * inv + beta1[256 + lane]) * Wf[256 + lane];
#pragma unroll
    for (int m = 32; m > 0; m >>= 1) d += __shfl_xor(d, m);
    if (lane == 0) out[row] = d + bf[0];
}

// ---------------------------------------------------------------------------
extern "C" void kernel_launch(void* const* d_in, const int* in_sizes, int n_in,
                              void* d_out, int out_size, void* d_ws, size_t ws_size,
                              hipStream_t stream)
{
    const float* x     = (const float*)d_in[0];
    const float* W0    = (const float*)d_in[1];
    const float* b0    = (const float*)d_in[2];
    const float* Wd0   = (const float*)d_in[3];
    const float* bd0   = (const float*)d_in[4];
    const float* beta0 = (const float*)d_in[5];
    const float* W1    = (const float*)d_in[6];
    const float* b1    = (const float*)d_in[7];
    const float* Wd1   = (const float*)d_in[8];
    const float* bd1   = (const float*)d_in[9];
    const float* beta1 = (const float*)d_in[10];
    const float* Wf    = (const float*)d_in[11];
    const float* bf    = (const float*)d_in[12];
    float* out = (float*)d_out;

    float* fws = (float*)d_ws;
    float* h0     = fws;                       // 1024*256
    float* h1     = h0 + 1024 * 256;           // 1024*256
    float* Mt0    = h1 + 1024 * 256;           // 10*1024*16
    float* Mt1    = Mt0 + 10 * 1024 * 16;      // 10*1024*16
    float* div0   = Mt1 + 10 * 1024 * 16;      // 1024*10
    float* div1   = div0 + 1024 * 10;          // 1024*10
    float* bcomb0 = div1 + 1024 * 10;          // 128
    float* bcomb1 = bcomb0 + 128;              // 128
    unsigned short* Wc0bT = (unsigned short*)(bcomb1 + 128);  // [128][512]
    unsigned short* Wc1bT = Wc0bT + 128 * 512;                // [128][296]
    unsigned short* a0b   = Wc1bT + 128 * 296;                // [1024][296]

    dim3 blk(256);

    prep_kernel<<<dim3(102), blk, 0, stream>>>(
        W0, Wd0, W1, Wd1, b0, bd0, b1, bd1, Wc0bT, Wc1bT, bcomb0, bcomb1);

    hm0_mfma<<<dim3(32, 12), blk, 0, stream>>>(
        x, W0, Wc0bT, b0, bcomb0, h0, Mt0);

    diversity_kernel<<<dim3(32, 10), blk, 0, stream>>>(Mt0, div0);

    ln0_kernel<<<dim3(256), blk, 0, stream>>>(h0, div0, beta0, a0b);

    hm1_mfma<<<dim3(32, 12), blk, 0, stream>>>(
        a0b, W1, Wc1bT, b1, bcomb1, h1, Mt1);

    diversity_kernel<<<dim3(32, 10), blk, 0, stream>>>(Mt1, div1);

    ln_final<<<dim3(256), blk, 0, stream>>>(h1, div1, beta1, Wf, bf, out);
}

// Round 20
// 61.382 us; speedup vs baseline: 1.3455x; 1.0016x over previous
//
#include <hip/hip_runtime.h>

typedef __attribute__((ext_vector_type(8))) short short8;
typedef __attribute__((ext_vector_type(4))) float f32x4;

#define EPS   1e-3f
#define ALPHA 0.3f

#define MFMA(a, b, c) __builtin_amdgcn_mfma_f32_16x16x32_bf16((a), (b), (c), 0, 0, 0)

__device__ __forceinline__ unsigned short f2bf(float f) {
    unsigned u = __float_as_uint(f);
    unsigned r = u + 0x7FFFu + ((u >> 16) & 1u);
    return (unsigned short)(r >> 16);
}
__device__ __forceinline__ float lrelu(float v) { return v > 0.f ? v : ALPHA * v; }

// ---------------------------------------------------------------------------
// N1 prep (102 blocks), all-MFMA Wc:
//   bid 0..63 : Wc0bT [128c][512f] bf16 from W0@Wd0 (tile 32f x 32c).
//   bid 64..99: Wc1bT [128c][296f] bf16 from W1(a<266)@Wd1.
//   bid 100/101: bcomb = b@Wd + bd — 2-way k-split, fully unrolled
//                (128 coalesced loads/thread, LDS combine).
// ---------------------------------------------------------------------------
__global__ __launch_bounds__(256) void prep_kernel(
    const float* __restrict__ W0, const float* __restrict__ Wd0,
    const float* __restrict__ W1, const float* __restrict__ Wd1,
    const float* __restrict__ b0, const float* __restrict__ bd0,
    const float* __restrict__ b1, const float* __restrict__ bd1,
    unsigned short* __restrict__ Wc0bT, unsigned short* __restrict__ Wc1bT,
    float* __restrict__ bcomb0, float* __restrict__ bcomb1)
{
    const int bid = blockIdx.x, t = threadIdx.x;
    if (bid < 100) {
        __shared__ unsigned short Ab[32][264];   // W rows (f-dim), k=256
        __shared__ unsigned short BbT[32][264];  // Wd^T rows (c-dim), k=256
        const float *Wsrc, *Wdsrc;
        unsigned short* Cdst;
        int ldc, ft, ct, arows;
        if (bid < 64) { ft = bid & 15; ct = bid >> 4; Wsrc = W0; Wdsrc = Wd0;
                        Cdst = Wc0bT; ldc = 512; arows = 512; }
        else { const int s = bid - 64; ft = s % 9; ct = s / 9;
               Wsrc = W1; Wdsrc = Wd1; Cdst = Wc1bT; ldc = 296; arows = 266; }

        {
            const int row = t >> 3, kc = t & 7;
            const int f = ft * 32 + row;
            if (f < arows) {
                const float* wp = Wsrc + (size_t)f * 256 + kc * 32;
#pragma unroll
                for (int i = 0; i < 8; ++i) {
                    const float4 v = ((const float4*)wp)[i];
                    Ab[row][kc * 32 + i * 4 + 0] = f2bf(v.x);
                    Ab[row][kc * 32 + i * 4 + 1] = f2bf(v.y);
                    Ab[row][kc * 32 + i * 4 + 2] = f2bf(v.z);
                    Ab[row][kc * 32 + i * 4 + 3] = f2bf(v.w);
                }
            } else {
#pragma unroll
                for (int i = 0; i < 8; ++i)
                    *(ushort4*)&Ab[row][kc * 32 + i * 4] = make_ushort4(0, 0, 0, 0);
            }
        }
        for (int idx = t; idx < 2048; idx += 256) {
            const int h = idx >> 3, c4 = idx & 7;
            const int cbase = ct * 32 + c4 * 4;
            float v[4];
            if (cbase + 3 < 100) {
                const float4 q = *(const float4*)&Wdsrc[(size_t)h * 100 + cbase];
                v[0] = q.x; v[1] = q.y; v[2] = q.z; v[3] = q.w;
            } else {
#pragma unroll
                for (int j = 0; j < 4; ++j)
                    v[j] = (cbase + j < 100) ? Wdsrc[(size_t)h * 100 + cbase + j] : 0.f;
            }
#pragma unroll
            for (int j = 0; j < 4; ++j) BbT[c4 * 4 + j][h] = f2bf(v[j]);
        }
        __syncthreads();

        const int lane = t & 63, w = t >> 6;
        const int cr = w & 1, fr = w >> 1, r = lane & 15, g = lane >> 4;
        const unsigned short* Ap = &BbT[cr * 16 + r][g * 8];
        const unsigned short* Bp = &Ab[fr * 16 + r][g * 8];
        f32x4 a0 = {0.f, 0.f, 0.f, 0.f}, a1 = {0.f, 0.f, 0.f, 0.f};
#pragma unroll
        for (int k0 = 0; k0 < 256; k0 += 64) {
            a0 = MFMA(*(const short8*)(Ap + k0),      *(const short8*)(Bp + k0),      a0);
            a1 = MFMA(*(const short8*)(Ap + k0 + 32), *(const short8*)(Bp + k0 + 32), a1);
        }
        const f32x4 acc = a0 + a1;
        const int crow = ct * 32 + cr * 16 + g * 4;
        const int fcol = ft * 32 + fr * 16 + r;
#pragma unroll
        for (int i = 0; i < 4; ++i)
            Cdst[(size_t)(crow + i) * ldc + fcol] = f2bf(acc[i]);
    } else {
        // --- bcomb: 2-way k-split (c = t&127, hc = t>>7), fully unrolled ---
        __shared__ float part[2][128];
        const float* bb = (bid == 100) ? b0 : b1;
        const float* Wd = (bid == 100) ? Wd0 : Wd1;
        const float* bd = (bid == 100) ? bd0 : bd1;
        float* o = (bid == 100) ? bcomb0 : bcomb1;

        const int c = t & 127, hc = t >> 7;
        float s = 0.f;
        if (c < 100) {
            const float* wp = Wd + (size_t)(hc * 128) * 100 + c;
            const float* bp = bb + hc * 128;
            float a0 = 0.f, a1 = 0.f, a2 = 0.f, a3 = 0.f;
            float a4 = 0.f, a5 = 0.f, a6 = 0.f, a7 = 0.f;
#pragma unroll
            for (int k = 0; k < 128; k += 8) {
                a0 += bp[k + 0] * wp[(k + 0) * 100];
                a1 += bp[k + 1] * wp[(k + 1) * 100];
                a2 += bp[k + 2] * wp[(k + 2) * 100];
                a3 += bp[k + 3] * wp[(k + 3) * 100];
                a4 += bp[k + 4] * wp[(k + 4) * 100];
                a5 += bp[k + 5] * wp[(k + 5) * 100];
                a6 += bp[k + 6] * wp[(k + 6) * 100];
                a7 += bp[k + 7] * wp[(k + 7) * 100];
            }
            s = ((a0 + a1) + (a2 + a3)) + ((a4 + a5) + (a6 + a7));
        }
        part[hc][c] = s;
        __syncthreads();
        if (t < 128)
            o[t] = (t < 100) ? (part[0][t] + part[1][t] + bd[t]) : 0.f;
    }
}

// ---------------------------------------------------------------------------
// N2 hm0: grid (32,12). yt<8: h0 = x@W0+b0; yt>=8: Mt0 = x@Wc0+bcomb0. K=512.
// B-stage for yt<8 float4-coalesced (16 rounds).
// ---------------------------------------------------------------------------
__global__ __launch_bounds__(256) void hm0_mfma(
    const float* __restrict__ x, const float* __restrict__ W0,
    const unsigned short* __restrict__ Wc0bT,
    const float* __restrict__ b0, const float* __restrict__ bcomb0,
    float* __restrict__ h0, float* __restrict__ Mt0)
{
    __shared__ unsigned short At[32][520];
    __shared__ unsigned short Bt[32][520];

    const int t = threadIdx.x, xt = blockIdx.x, yt = blockIdx.y;

    {
        const int row = t >> 3, kc = t & 7;
        const float* xp = x + (size_t)(xt * 32 + row) * 512 + kc * 64;
#pragma unroll
        for (int i = 0; i < 8; ++i) {
            const float4 lo = ((const float4*)xp)[i * 2];
            const float4 hi = ((const float4*)xp)[i * 2 + 1];
            short8 p;
            p[0] = f2bf(lo.x); p[1] = f2bf(lo.y); p[2] = f2bf(lo.z); p[3] = f2bf(lo.w);
            p[4] = f2bf(hi.x); p[5] = f2bf(hi.y); p[6] = f2bf(hi.z); p[7] = f2bf(hi.w);
            *(short8*)&At[row][kc * 64 + i * 8] = p;
        }
    }
    if (yt < 8) {
        const int kr = t >> 3, nf = t & 7;
#pragma unroll
        for (int rnd = 0; rnd < 16; ++rnd) {
            const int k = kr + rnd * 32;
            const float4 v = *(const float4*)&W0[(size_t)k * 256 + yt * 32 + nf * 4];
            Bt[nf * 4 + 0][k] = f2bf(v.x);
            Bt[nf * 4 + 1][k] = f2bf(v.y);
            Bt[nf * 4 + 2][k] = f2bf(v.z);
            Bt[nf * 4 + 3][k] = f2bf(v.w);
        }
    } else {
        const int c = t >> 3, kc = t & 7;
        const unsigned short* bp = Wc0bT + (size_t)((yt - 8) * 32 + c) * 512 + kc * 64;
#pragma unroll
        for (int i = 0; i < 8; ++i)
            *(short8*)&Bt[c][kc * 64 + i * 8] = ((const short8*)bp)[i];
    }
    __syncthreads();

    const int lane = t & 63, w = t >> 6;
    const int wr = w >> 1, wn = w & 1, r = lane & 15, g = lane >> 4;
    const int lrA = wr * 16 + r, lrB = wn * 16 + r;
    f32x4 a0 = {0.f, 0.f, 0.f, 0.f}, a1 = {0.f, 0.f, 0.f, 0.f};
#pragma unroll
    for (int k0 = 0; k0 < 512; k0 += 64) {
        a0 = MFMA(*(const short8*)&At[lrA][k0 + g * 8],
                  *(const short8*)&Bt[lrB][k0 + g * 8], a0);
        a1 = MFMA(*(const short8*)&At[lrA][k0 + 32 + g * 8],
                  *(const short8*)&Bt[lrB][k0 + 32 + g * 8], a1);
    }
    const f32x4 acc = a0 + a1;
    const int orow0 = xt * 32 + wr * 16 + g * 4;

    if (yt < 8) {
        const int bcol = yt * 32 + wn * 16 + r;
        const float bv = b0[bcol];
#pragma unroll
        for (int i = 0; i < 4; ++i)
            h0[(size_t)(orow0 + i) * 256 + bcol] = acc[i] + bv;
    } else {
        const int c = (yt - 8) * 32 + wn * 16 + r;
        if (c < 100) {
            const int kq = c / 10, d = c - kq * 10;
            const float bv = bcomb0[c];
            float* dst = Mt0 + (size_t)kq * (1024 * 16) + (size_t)orow0 * 16 + d;
#pragma unroll
            for (int i = 0; i < 4; ++i) dst[i * 16] = acc[i] + bv;
        }
    }
}

// ---------------------------------------------------------------------------
// N5 hm1: grid (32,12). A = a0b bf16 [1024][296]. yt<8: h1; yt>=8: Mt1. K=288.
// B-stage for yt<8 float4-coalesced (9 rounds, k<266 zero-guard).
// ---------------------------------------------------------------------------
__global__ __launch_bounds__(256) void hm1_mfma(
    const unsigned short* __restrict__ a0b, const float* __restrict__ W1,
    const unsigned short* __restrict__ Wc1bT,
    const float* __restrict__ b1, const float* __restrict__ bcomb1,
    float* __restrict__ h1, float* __restrict__ Mt1)
{
    __shared__ unsigned short At[32][296];
    __shared__ unsigned short Bt[32][296];

    const int t = threadIdx.x, xt = blockIdx.x, yt = blockIdx.y;

    {
        const int row = t >> 3, kc = t & 7;
        const unsigned short* ap = a0b + (size_t)(xt * 32 + row) * 296;
        for (int i = kc; i < 37; i += 8)
            *(short8*)&At[row][i * 8] = ((const short8*)ap)[i];
    }
    if (yt < 8) {
        const int kr = t >> 3, nf = t & 7;
#pragma unroll
        for (int rnd = 0; rnd < 9; ++rnd) {
            const int k = kr + rnd * 32;
            float4 v = make_float4(0.f, 0.f, 0.f, 0.f);
            if (k < 266) v = *(const float4*)&W1[(size_t)k * 256 + yt * 32 + nf * 4];
            Bt[nf * 4 + 0][k] = f2bf(v.x);
            Bt[nf * 4 + 1][k] = f2bf(v.y);
            Bt[nf * 4 + 2][k] = f2bf(v.z);
            Bt[nf * 4 + 3][k] = f2bf(v.w);
        }
    } else {
        const int c = t >> 3, kc = t & 7;
        const unsigned short* bp = Wc1bT + (size_t)((yt - 8) * 32 + c) * 296;
        for (int i = kc; i < 37; i += 8)
            *(short8*)&Bt[c][i * 8] = ((const short8*)bp)[i];
    }
    __syncthreads();

    const int lane = t & 63, w = t >> 6;
    const int wr = w >> 1, wn = w & 1, r = lane & 15, g = lane >> 4;
    const int lrA = wr * 16 + r, lrB = wn * 16 + r;
    f32x4 a0 = {0.f, 0.f, 0.f, 0.f}, a1 = {0.f, 0.f, 0.f, 0.f};
#pragma unroll
    for (int k0 = 0; k0 < 256; k0 += 64) {
        a0 = MFMA(*(const short8*)&At[lrA][k0 + g * 8],
                  *(const short8*)&Bt[lrB][k0 + g * 8], a0);
        a1 = MFMA(*(const short8*)&At[lrA][k0 + 32 + g * 8],
                  *(const short8*)&Bt[lrB][k0 + 32 + g * 8], a1);
    }
    a0 = MFMA(*(const short8*)&At[lrA][256 + g * 8],
              *(const short8*)&Bt[lrB][256 + g * 8], a0);
    const f32x4 acc = a0 + a1;
    const int orow0 = xt * 32 + wr * 16 + g * 4;

    if (yt < 8) {
        const int bcol = yt * 32 + wn * 16 + r;
        const float bv = b1[bcol];
#pragma unroll
        for (int i = 0; i < 4; ++i)
            h1[(size_t)(orow0 + i) * 256 + bcol] = acc[i] + bv;
    } else {
        const int c = (yt - 8) * 32 + wn * 16 + r;
        if (c < 100) {
            const int kq = c / 10, d = c - kq * 10;
            const float bv = bcomb1[c];
            float* dst = Mt1 + (size_t)kq * (1024 * 16) + (size_t)orow0 * 16 + d;
#pragma unroll
            for (int i = 0; i < 4; ++i) dst[i * 16] = acc[i] + bv;
        }
    }
}

// ---------------------------------------------------------------------------
// N3/N6 diversity: grid (32,10). Mt slice [1024][16] staged coalesced.
// Pair loop unrolled x4 for ILP.
// ---------------------------------------------------------------------------
__global__ __launch_bounds__(256) void diversity_kernel(
    const float* __restrict__ Mt, float* __restrict__ divOut)
{
    __shared__ float Ms[1024 * 16];
    __shared__ float red[256];

    const int t = threadIdx.x;
    const float* src = Mt + (size_t)blockIdx.y * (1024 * 16);
    for (int i = t; i < 1024 * 4; i += 256)
        ((float4*)Ms)[i] = ((const float4*)src)[i];
    __syncthreads();

    const int il = t & 31, jc = t >> 5;
    const int i = blockIdx.x * 32 + il;

    const float4 m0 = *(const float4*)&Ms[i * 16];
    const float4 m1 = *(const float4*)&Ms[i * 16 + 4];
    const float2 m2 = *(const float2*)&Ms[i * 16 + 8];

    float acc = 0.f;
    const int jB = jc * 128;
#pragma unroll 4
    for (int j = jB; j < jB + 128; ++j) {
        const float4 v0 = *(const float4*)&Ms[j * 16];
        const float4 v1 = *(const float4*)&Ms[j * 16 + 4];
        const float2 v2 = *(const float2*)&Ms[j * 16 + 8];
        float l1 = fabsf(m0.x - v0.x) + fabsf(m0.y - v0.y)
                 + fabsf(m0.z - v0.z) + fabsf(m0.w - v0.w)
                 + fabsf(m1.x - v1.x) + fabsf(m1.y - v1.y)
                 + fabsf(m1.z - v1.z) + fabsf(m1.w - v1.w)
                 + fabsf(m2.x - v2.x) + fabsf(m2.y - v2.y);
        acc += __expf(-l1);
    }

    red[t] = acc;
    __syncthreads();
    if (t < 32) {
        float s = 0.f;
#pragma unroll
        for (int c = 0; c < 8; ++c) s += red[c * 32 + t];
        divOut[(size_t)(blockIdx.x * 32 + t) * 10 + blockIdx.y] = s;
    }
}

// ---------------------------------------------------------------------------
// N4 ln0: 256 blocks x 4 waves; one row per wave. LN + lrelu -> a0b [1024][296].
// ---------------------------------------------------------------------------
__global__ __launch_bounds__(256) void ln0_kernel(
    const float* __restrict__ h0, const float* __restrict__ div0,
    const float* __restrict__ beta0, unsigned short* __restrict__ a0b)
{
    const int t = threadIdx.x, lane = t & 63;
    const int row = blockIdx.x * 4 + (t >> 6);

    const float4 hv = ((const float4*)(h0 + (size_t)row * 256))[lane];
    const float dv = (lane < 10) ? div0[(size_t)row * 10 + lane] : 0.f;

    float s = hv.x + hv.y + hv.z + hv.w + dv;
    float q = hv.x * hv.x + hv.y * hv.y + hv.z * hv.z + hv.w * hv.w + dv * dv;
#pragma unroll
    for (int m = 32; m > 0; m >>= 1) { s += __shfl_xor(s, m); q += __shfl_xor(q, m); }

    const float mean = s * (1.f / 266.f);
    const float var  = q * (1.f / 266.f) - mean * mean;
    const float inv  = rsqrtf(var + EPS);

    const float4 bv = ((const float4*)beta0)[lane];
    ushort4 o;
    o.x = f2bf(lrelu((hv.x - mean) * inv + bv.x));
    o.y = f2bf(lrelu((hv.y - mean) * inv + bv.y));
    o.z = f2bf(lrelu((hv.z - mean) * inv + bv.z));
    o.w = f2bf(lrelu((hv.w - mean) * inv + bv.w));
    *(ushort4*)&a0b[(size_t)row * 296 + lane * 4] = o;

    if (lane < 10)
        a0b[(size_t)row * 296 + 256 + lane] = f2bf(lrelu((dv - mean) * inv + beta0[256 + lane]));
    else if (lane >= 16 && lane < 46)
        a0b[(size_t)row * 296 + 250 + lane] = 0;   // cols 266..295 zero
}

// ---------------------------------------------------------------------------
// N7 ln_final: 256 blocks x 4 waves; LN + lrelu + dot(Wf) + bf.
// ---------------------------------------------------------------------------
__global__ __launch_bounds__(256) void ln_final(
    const float* __restrict__ h1, const float* __restrict__ div1,
    const float* __restrict__ beta1, const float* __restrict__ Wf,
    const float* __restrict__ bf, float* __restrict__ out)
{
    const int t = threadIdx.x, lane = t & 63;
    const int row = blockIdx.x * 4 + (t >> 6);

    const float4 hv = ((const float4*)(h1 + (size_t)row * 256))[lane];
    const float dv = (lane < 10) ? div1[(size_t)row * 10 + lane] : 0.f;

    float s = hv.x + hv.y + hv.z + hv.w + dv;
    float q = hv.x * hv.x + hv.y * hv.y + hv.z * hv.z + hv.w * hv.w + dv * dv;
#pragma unroll
    for (int m = 32; m > 0; m >>= 1) { s += __shfl_xor(s, m); q += __shfl_xor(q, m); }

    const float mean = s * (1.f / 266.f);
    const float var  = q * (1.f / 266.f) - mean * mean;
    const float inv  = rsqrtf(var + EPS);

    const float4 bv = ((const float4*)beta1)[lane];
    const float4 wf = ((const float4*)Wf)[lane];
    float d = lrelu((hv.x - mean) * inv + bv.x) * wf.x
            + lrelu((hv.y - mean) * inv + bv.y) * wf.y
            + lrelu((hv.z - mean) * inv + bv.z) * wf.z
            + lrelu((hv.w - mean) * inv + bv.w) * wf.w;
    if (lane < 10)
        d += lrelu((dv - mean) * inv + beta1[256 + lane]) * Wf[256 + lane];
#pragma unroll
    for (int m = 32; m > 0; m >>= 1) d += __shfl_xor(d, m);
    if (lane == 0) out[row] = d + bf[0];
}

// ---------------------------------------------------------------------------
extern "C" void kernel_launch(void* const* d_in, const int* in_sizes, int n_in,
                              void* d_out, int out_size, void* d_ws, size_t ws_size,
                              hipStream_t stream)
{
    const float* x     = (const float*)d_in[0];
    const float* W0    = (const float*)d_in[1];
    const float* b0    = (const float*)d_in[2];
    const float* Wd0   = (const float*)d_in[3];
    const float* bd0   = (const float*)d_in[4];
    const float* beta0 = (const float*)d_in[5];
    const float* W1    = (const float*)d_in[6];
    const float* b1    = (const float*)d_in[7];
    const float* Wd1   = (const float*)d_in[8];
    const float* bd1   = (const float*)d_in[9];
    const float* beta1 = (const float*)d_in[10];
    const float* Wf    = (const float*)d_in[11];
    const float* bf    = (const float*)d_in[12];
    float* out = (float*)d_out;

    float* fws = (float*)d_ws;
    float* h0     = fws;                       // 1024*256
    float* h1     = h0 + 1024 * 256;           // 1024*256
    float* Mt0    = h1 + 1024 * 256;           // 10*1024*16
    float* Mt1    = Mt0 + 10 * 1024 * 16;      // 10*1024*16
    float* div0   = Mt1 + 10 * 1024 * 16;      // 1024*10
    float* div1   = div0 + 1024 * 10;          // 1024*10
    float* bcomb0 = div1 + 1024 * 10;          // 128
    float* bcomb1 = bcomb0 + 128;              // 128
    unsigned short* Wc0bT = (unsigned short*)(bcomb1 + 128);  // [128][512]
    unsigned short* Wc1bT = Wc0bT + 128 * 512;                // [128][296]
    unsigned short* a0b   = Wc1bT + 128 * 296;                // [1024][296]

    dim3 blk(256);

    prep_kernel<<<dim3(102), blk, 0, stream>>>(
        W0, Wd0, W1, Wd1, b0, bd0, b1, bd1, Wc0bT, Wc1bT, bcomb0, bcomb1);

    hm0_mfma<<<dim3(32, 12), blk, 0, stream>>>(
        x, W0, Wc0bT, b0, bcomb0, h0, Mt0);

    diversity_kernel<<<dim3(32, 10), blk, 0, stream>>>(Mt0, div0);

    ln0_kernel<<<dim3(256), blk, 0, stream>>>(h0, div0, beta0, a0b);

    hm1_mfma<<<dim3(32, 12), blk, 0, stream>>>(
        a0b, W1, Wc1bT, b1, bcomb1, h1, Mt1);

    diversity_kernel<<<dim3(32, 10), blk, 0, stream>>>(Mt1, div1);

    ln_final<<<dim3(256), blk, 0, stream>>>(h1, div1, beta1, Wf, bf, out);
}